// Round 1
// baseline (96.579 us; speedup 1.0000x reference)
//
#include <hip/hip_runtime.h>
#include <hip/hip_bf16.h>

// Decoder_45509473468804
//
// Key insight: the reference applies LayerNorm over the LAST dim, whose size
// is OUT == 1. For a size-1 normalized dim:
//     mu  = mean(h, -1) == h            (exactly; mean of one element)
//     h - mu == 0.0                     (exact in IEEE fp: x - x == 0)
//     var == 0.0                        (exact)
//     out = 0 * rsqrt(0 + eps) * gamma + beta == beta   (bit-exact)
// So the gather + 4-layer MLP is dead code and the output is ln_beta[0]
// broadcast to all N_EDGES * OUT = 3,200,000 fp32 elements. absmax vs the
// reference is exactly 0.
//
// This reduces the kernel to a 12.8 MB broadcast store — write-BW bound
// (~2 us at 6.3 TB/s) plus launch overhead.

__global__ __launch_bounds__(256) void Decoder_45509473468804_kernel(
    const float* __restrict__ ln_beta,
    float* __restrict__ out,
    int n)  // total fp32 elements
{
    const float b = ln_beta[0];
    const int n4 = n >> 2;  // float4 count
    const float4 v = make_float4(b, b, b, b);

    float4* __restrict__ out4 = reinterpret_cast<float4*>(out);
    int i = blockIdx.x * blockDim.x + threadIdx.x;
    const int stride = gridDim.x * blockDim.x;
    for (; i < n4; i += stride) {
        out4[i] = v;
    }

    // Tail (n % 4 != 0) — 3.2M is divisible by 4, but keep it general.
    const int tail_start = n4 << 2;
    if (blockIdx.x == 0) {
        for (int t = tail_start + threadIdx.x; t < n; t += blockDim.x) {
            out[t] = b;
        }
    }
}

extern "C" void kernel_launch(void* const* d_in, const int* in_sizes, int n_in,
                              void* d_out, int out_size, void* d_ws, size_t ws_size,
                              hipStream_t stream) {
    // Input order (setup_inputs dict order):
    //  0 x_node, 1 edge_index, 2 W1, 3 b1, 4 W2, 5 b2, 6 W3, 7 b3,
    //  8 W4, 9 b4, 10 ln_gamma, 11 ln_beta
    const float* ln_beta = (const float*)d_in[11];
    float* out = (float*)d_out;

    const int n = out_size;          // 3,200,000 fp32
    const int n4 = n >> 2;           // 800,000 float4 stores
    const int block = 256;
    int grid = (n4 + block - 1) / block;  // 3125 blocks
    if (grid < 1) grid = 1;

    Decoder_45509473468804_kernel<<<grid, block, 0, stream>>>(ln_beta, out, n);
}